// Round 1
// baseline (1456.877 us; speedup 1.0000x reference)
//
#include <hip/hip_runtime.h>
#include <hip/hip_fp16.h>
#include <hip/hip_cooperative_groups.h>
#include <math.h>

namespace cg = cooperative_groups;

#define B_ 128
#define C_ 10
#define R_ 8192
#define I_ 8
#define O_ 16

typedef __attribute__((ext_vector_type(8))) _Float16 half8;
typedef __attribute__((ext_vector_type(16))) float f32x16;

#define XROW 512           // uints per x r-row: 128 b * 4
#define WROW 64            // uints per W row: 16 o * 4
#define WZERO 80           // zero-row index (block-diagonal A trick)
#define SBO (C_ * B_ * O_) // 20480
#define NTILES (R_ / 8)    // 1024

__device__ __forceinline__ unsigned pk2(float a, float b) {
    __half2 h = __floats2half2_rn(a, b);
    return *(unsigned*)&h;
}

// Stage one 8-r tile: x as fp16 [r][b][4xb32], W (all 10 c) as fp16 [c*8+r][o][4xb32].
__device__ __forceinline__ void stage_tile(int tile, int tid,
                                           unsigned* xls, unsigned* wls,
                                           const float* __restrict__ x,
                                           const float* __restrict__ w) {
    const int r0 = tile * 8;
#pragma unroll
    for (int k = 0; k < 8; ++k) {
        const int f = k * 256 + tid;            // 0..2047
        const int bb = f >> 4;
        const int rr = (f >> 1) & 7;
        const int q = f & 1;
        const float4 v = *(const float4*)(x + ((size_t)bb * R_ + r0 + rr) * 8 + q * 4);
        *(uint2*)(xls + rr * XROW + bb * 4 + q * 2) = make_uint2(pk2(v.x, v.y), pk2(v.z, v.w));
    }
#pragma unroll
    for (int k = 0; k < 5; ++k) {
        const int id = k * 256 + tid;           // 0..1279 = (c, r, o)
        const int o = id & 15;
        const int r = (id >> 4) & 7;
        const int c = id >> 7;
        const float* wp = w + ((size_t)(c * R_ + r0 + r) * 8) * 16 + o;
        const float f0 = wp[0],  f1 = wp[16],  f2 = wp[32],  f3 = wp[48];
        const float f4 = wp[64], f5 = wp[80],  f6 = wp[96],  f7 = wp[112];
        *(uint4*)(wls + (c * 8 + r) * WROW + o * 4) =
            make_uint4(pk2(f0, f1), pk2(f2, f3), pk2(f4, f5), pk2(f6, f7));
    }
    if (tid < WROW) wls[WZERO * WROW + tid] = 0u;
    __syncthreads();
}

// ---------------------------------------------------------------------------
// fused_all: all 3 routing iterations in ONE cooperative kernel.
// grid 1024 (one 8-r tile per block, exactly co-resident: 37.4KB LDS -> 4/CU),
// block 256. x/W staged to LDS ONCE and reused by all 3 iterations.
// Per iteration: phaseA (partials -> part fp16) | grid.sync |
//                phaseB (64-slot tree reduce -> part2 f32) | grid.sync |
//                phaseC (final sum + squash -> vsum/out)   | grid.sync.
// __threadfence() around each sync: release (wbL2) + acquire (invL2) for
// cross-XCD visibility of part/part2/vsum (Guideline 16).
// Fallback: if occupancy < 4/CU the host launches fewer blocks and each block
// grid-strides tiles, re-staging per tile (slower, still correct).
// ---------------------------------------------------------------------------
__global__ __launch_bounds__(256, 4) void fused_all(
        const float* __restrict__ x, const float* __restrict__ w,
        __half* __restrict__ part, float* __restrict__ part2,
        float* __restrict__ vsum, float* __restrict__ out) {
    __shared__ unsigned xls[8 * XROW];          // 16 KB
    __shared__ unsigned wls[(80 + 1) * WROW];   // 20.25 KB

    cg::grid_group grid = cg::this_grid();

    const int tid  = threadIdx.x;
    const int wave = tid >> 6;
    const int lane = tid & 63;
    const int n    = lane & 31;
    const int g    = lane >> 5;            // k-half / o-half selector
    const int rp_m = (lane & 31) >> 4;     // r' of this lane's A row
    const int o_m  = lane & 15;            // o of this lane's A row
    const int b    = wave * 32 + n;        // global batch 0..127
    const int G    = gridDim.x;
    const int bid  = blockIdx.x;
    const bool single = (G == NTILES);
    const int act  = (g == rp_m);

    if (single) stage_tile(bid, tid, xls, wls, x, w);   // stage ONCE for all 3 iters

    for (int it = 0; it < 3; ++it) {
        const int mode = (it > 0);

        // ================= PHASE A: per-tile partial s sums =================
        for (int tile = bid; tile < NTILES; tile += G) {
            if (!single) {
                __syncthreads();                    // WAR guard on LDS
                stage_tile(tile, tid, xls, wls, x, w);
            }

            float dacc[8];
            if (mode) {
                // ---- softmax denominators over c, per (r, b) ----
#pragma unroll
                for (int j = 0; j < 8; ++j) dacc[j] = 0.f;
#pragma unroll 1
                for (int c = 0; c < C_; ++c) {
                    const float4* vp = (const float4*)(vsum + ((size_t)c * B_ + b) * O_ + 4 * g);
                    const float4 va = vp[0];   // o = 4g..4g+3
                    const float4 vb = vp[2];   // o = 8+4g..
#pragma unroll
                    for (int rp = 0; rp < 4; ++rp) {
                        const int woff = act ? ((c * 8 + 2 * rp + g) * WROW + o_m * 4)
                                             : (WZERO * WROW);
                        const half8 a  = *(const half8*)(wls + woff);
                        const half8 xb = *(const half8*)(xls + (2 * rp + g) * XROW + b * 4);
                        f32x16 u;
#pragma unroll
                        for (int j = 0; j < 16; ++j) u[j] = 0.f;
                        u = __builtin_amdgcn_mfma_f32_32x32x16_f16(a, xb, u, 0, 0, 0);
                        float p0 = u[0] * va.x + u[1] * va.y + u[2] * va.z + u[3] * va.w
                                 + u[4] * vb.x + u[5] * vb.y + u[6] * vb.z + u[7] * vb.w;
                        float p1 = u[8] * va.x + u[9] * va.y + u[10] * va.z + u[11] * va.w
                                 + u[12] * vb.x + u[13] * vb.y + u[14] * vb.z + u[15] * vb.w;
                        p0 += __shfl_xor(p0, 32);
                        p1 += __shfl_xor(p1, 32);
                        dacc[2 * rp]     += __expf(p0);
                        dacc[2 * rp + 1] += __expf(p1);
                    }
                }
#pragma unroll
                for (int j = 0; j < 8; ++j) dacc[j] = 1.0f / dacc[j];
            }

            // ---- weighted accumulation ----
#pragma unroll 1
            for (int c = 0; c < C_; ++c) {
                float4 va, vb;
                if (mode) {
                    const float4* vp = (const float4*)(vsum + ((size_t)c * B_ + b) * O_ + 4 * g);
                    va = vp[0]; vb = vp[2];
                }
                f32x16 acc;
#pragma unroll
                for (int j = 0; j < 16; ++j) acc[j] = 0.f;

#pragma unroll
                for (int rp = 0; rp < 4; ++rp) {
                    const int woff = act ? ((c * 8 + 2 * rp + g) * WROW + o_m * 4)
                                         : (WZERO * WROW);
                    const half8 a  = *(const half8*)(wls + woff);
                    const half8 xb = *(const half8*)(xls + (2 * rp + g) * XROW + b * 4);
                    if (mode) {
                        f32x16 u;
#pragma unroll
                        for (int j = 0; j < 16; ++j) u[j] = 0.f;
                        u = __builtin_amdgcn_mfma_f32_32x32x16_f16(a, xb, u, 0, 0, 0);
                        float p0 = u[0] * va.x + u[1] * va.y + u[2] * va.z + u[3] * va.w
                                 + u[4] * vb.x + u[5] * vb.y + u[6] * vb.z + u[7] * vb.w;
                        float p1 = u[8] * va.x + u[9] * va.y + u[10] * va.z + u[11] * va.w
                                 + u[12] * vb.x + u[13] * vb.y + u[14] * vb.z + u[15] * vb.w;
                        p0 += __shfl_xor(p0, 32);
                        p1 += __shfl_xor(p1, 32);
                        const float c0 = __expf(p0) * dacc[2 * rp];
                        const float c1 = __expf(p1) * dacc[2 * rp + 1];
#pragma unroll
                        for (int j = 0; j < 8; ++j)  acc[j] += c0 * u[j];
#pragma unroll
                        for (int j = 8; j < 16; ++j) acc[j] += c1 * u[j];
                    } else {
                        // iter 0: uniform weights -> chain MFMAs through C operand,
                        // scale by 0.1 once at the end (saves inits + weight FMAs)
                        acc = __builtin_amdgcn_mfma_f32_32x32x16_f16(a, xb, acc, 0, 0, 0);
                    }
                }

                const float sc = mode ? 1.0f : 0.1f;
                const float f0 = (acc[0] + acc[8])  * sc, f1 = (acc[1] + acc[9])  * sc;
                const float f2 = (acc[2] + acc[10]) * sc, f3 = (acc[3] + acc[11]) * sc;
                const float f4 = (acc[4] + acc[12]) * sc, f5 = (acc[5] + acc[13]) * sc;
                const float f6 = (acc[6] + acc[14]) * sc, f7 = (acc[7] + acc[15]) * sc;
                __half* pp = part + (((size_t)tile * C_ + c) * B_ + b) * O_;
                *(uint2*)(pp + 4 * g)     = make_uint2(pk2(f0, f1), pk2(f2, f3));
                *(uint2*)(pp + 8 + 4 * g) = make_uint2(pk2(f4, f5), pk2(f6, f7));
            }
        }
        __threadfence();
        grid.sync();
        __threadfence();

        // ================= PHASE B: 64-slot tree reduce =================
        for (int un = bid; un < 1280; un += G) {
            const int t  = (un % 80) * 256 + tid;
            const int s0 = (un / 80) * 64;
            const __half* p = part + (size_t)s0 * SBO + t;
            float sum = 0.f;
#pragma unroll 8
            for (int s = 0; s < 64; ++s)
                sum += __half2float(p[(size_t)s * SBO]);
            part2[(size_t)(un / 80) * SBO + t] = sum;
        }
        __threadfence();
        grid.sync();
        __threadfence();

        // ================= PHASE C: final sum + squash =================
        for (int un = bid; un < 80; un += G) {
            const int t = un * 256 + tid;
            float sum = 0.f;
#pragma unroll
            for (int s = 0; s < 16; ++s)
                sum += part2[(size_t)s * SBO + t];

            float sq = sum * sum;
            sq += __shfl_xor(sq, 1);
            sq += __shfl_xor(sq, 2);
            sq += __shfl_xor(sq, 4);
            sq += __shfl_xor(sq, 8);
            const float scale = sq / ((1.0f + sq) * sqrtf(sq + 1e-8f));
            const float v = scale * sum;

            if (it == 0) {
                vsum[t] = v;                        // b_ij = u.v1
            } else if (it == 1) {
                vsum[t] += v;                       // b_ij = u.(v1+v2)
            } else {
                const int o = t & 15, bb = (t >> 4) & 127, c = t >> 11;
                out[((size_t)bb * C_ + c) * O_ + o] = v;
            }
        }
        if (it < 2) {
            __threadfence();
            grid.sync();
            __threadfence();
        }
    }
}

extern "C" void kernel_launch(void* const* d_in, const int* in_sizes, int n_in,
                              void* d_out, int out_size, void* d_ws, size_t ws_size,
                              hipStream_t stream) {
    const float* x = (const float*)d_in[0];   // [B,R,8]
    const float* w = (const float*)d_in[1];   // [C,R,8,16]
    float* out = (float*)d_out;               // [B,C,16]

    __half* part = (__half*)d_ws;                           // 1024*20480 fp16 = 41.9 MB
    float* part2 = (float*)(part + (size_t)NTILES * SBO);   // 16*20480 fp32 = 1.3 MB
    float* vsum  = part2 + (size_t)16 * SBO;                // 20480 f ([C][B][16])

    // Cooperative grid must be exactly co-resident. Expect 4 blocks/CU * 256 CU
    // = 1024 (LDS 37.4KB -> 4/CU, VGPR capped at 128 by __launch_bounds__(256,4)).
    static int G = 0;
    if (G == 0) {
        int nb = 0;
        if (hipOccupancyMaxActiveBlocksPerMultiprocessor(
                &nb, (const void*)fused_all, 256, 0) != hipSuccess || nb < 1)
            nb = 4;
        int ncu = 256;
        hipDeviceProp_t prop;
        int dev = 0;
        hipGetDevice(&dev);
        if (hipGetDeviceProperties(&prop, dev) == hipSuccess && prop.multiProcessorCount > 0)
            ncu = prop.multiProcessorCount;
        long g = (long)nb * ncu;
        if (g > NTILES) g = NTILES;
        if (g < 1) g = 1;
        G = (int)g;
    }

    void* args[] = {(void*)&x, (void*)&w, (void*)&part, (void*)&part2,
                    (void*)&vsum, (void*)&out};
    hipLaunchCooperativeKernel((const void*)fused_all, dim3(G), dim3(256),
                               args, 0, stream);
}

// Round 2
// 317.969 us; speedup vs baseline: 4.5818x; 4.5818x over previous
//
#include <hip/hip_runtime.h>
#include <hip/hip_fp16.h>
#include <math.h>

#define B_ 128
#define C_ 10
#define R_ 8192
#define I_ 8
#define O_ 16

typedef __attribute__((ext_vector_type(8))) _Float16 half8;
typedef __attribute__((ext_vector_type(16))) float f32x16;

#define XROW 512           // uints per x r-row: 128 b * 4
#define WROW 64            // uints per W row: 16 o * 4
#define WZERO 80           // zero-row index (block-diagonal A trick)
#define SBO (C_ * B_ * O_) // 20480

__device__ __forceinline__ unsigned pk2(float a, float b) {
    __half2 h = __floats2half2_rn(a, b);
    return *(unsigned*)&h;
}

// ---------------------------------------------------------------------------
// fused_iter: one routing iteration. grid 1024 (r-tiles of 8), block 256.
// All 10 c's W tiles staged once as fp16 (20.3 KB) + x tile fp16 (16 KB).
// Per (c, r-pair): ONE 32x32x16 f16 MFMA computes u[2r x 16o][32b].
// mode 1 changes vs round-0 (all numerically bit-identical):
//  - phase2: ONE shfl + ONE exp per (c,rp): exchange partial_{1-g}, keep p_g.
//  - e[c][rp] = exp(p_own_r) carried in 40 VGPRs (full c-unroll -> static idx);
//    phase3 skips the dot/shfl/exp recompute; partner's weight via shfl_xor(w,32).
//  - hoisted zero16 as MFMA C operand (no per-use 16-wide init).
//  - mode 0 chains the 4 rp-MFMAs through the C operand, scales 0.1 once.
// Output: part[slot=blockIdx.x][c][b][o] fp16 partial s sums.
// ---------------------------------------------------------------------------
__global__ __launch_bounds__(256, 4) void fused_iter(const float* __restrict__ x,
                                                     const float* __restrict__ w,
                                                     const float* __restrict__ vsum,  // [C][B][16]
                                                     __half* __restrict__ part,
                                                     int mode) {
    __shared__ unsigned xls[8 * XROW];          // 16 KB
    __shared__ unsigned wls[(80 + 1) * WROW];   // 20.25 KB

    const int tid = threadIdx.x;
    const int wave = tid >> 6;
    const int lane = tid & 63;
    const int n = lane & 31;
    const int g = lane >> 5;            // k-half / o-half selector
    const int rp_m = (lane & 31) >> 4;  // r' of this lane's A row
    const int o_m = lane & 15;          // o of this lane's A row
    const int b = wave * 32 + n;        // global batch 0..127
    const int r0 = blockIdx.x * 8;

    // ---- stage x tile fp16: xls[r][b][4 b32], once ----
#pragma unroll
    for (int k = 0; k < 8; ++k) {
        const int f = k * 256 + tid;            // 0..2047
        const int bb = f >> 4;
        const int rr = (f >> 1) & 7;
        const int q = f & 1;
        const float4 v = *(const float4*)(x + ((size_t)bb * R_ + r0 + rr) * 8 + q * 4);
        *(uint2*)(xls + rr * XROW + bb * 4 + q * 2) = make_uint2(pk2(v.x, v.y), pk2(v.z, v.w));
    }
    // ---- stage W for ALL c fp16: wls[c*8+r][o][4 b32], once ----
#pragma unroll
    for (int k = 0; k < 5; ++k) {
        const int id = k * 256 + tid;           // 0..1279 = (c, r, o)
        const int o = id & 15;
        const int r = (id >> 4) & 7;
        const int c = id >> 7;
        const float* wp = w + ((size_t)(c * R_ + r0 + r) * 8) * 16 + o;
        const float f0 = wp[0],  f1 = wp[16],  f2 = wp[32],  f3 = wp[48];
        const float f4 = wp[64], f5 = wp[80],  f6 = wp[96],  f7 = wp[112];
        *(uint4*)(wls + (c * 8 + r) * WROW + o * 4) =
            make_uint4(pk2(f0, f1), pk2(f2, f3), pk2(f4, f5), pk2(f6, f7));
    }
    if (tid < WROW) wls[WZERO * WROW + tid] = 0u;
    __syncthreads();

    const int act = (g == rp_m);

    // hoisted zero accumulator: MFMA C operand (D != C), no per-use init
    f32x16 zero16;
#pragma unroll
    for (int j = 0; j < 16; ++j) zero16[j] = 0.f;

    if (mode) {
        // ================= mode 1: softmax-weighted =================
        float e[C_][4];     // exp(p) for THIS lane's r = 2rp+g (static idx via unroll)
        float dinv[4];
        {
            float dacc[4] = {0.f, 0.f, 0.f, 0.f};
#pragma unroll
            for (int c = 0; c < C_; ++c) {
                const float4* vp = (const float4*)(vsum + ((size_t)c * B_ + b) * O_ + 4 * g);
                const float4 va = vp[0];   // o = 4g..4g+3
                const float4 vb = vp[2];   // o = 8+4g..
#pragma unroll
                for (int rp = 0; rp < 4; ++rp) {
                    const int woff = act ? ((c * 8 + 2 * rp + g) * WROW + o_m * 4)
                                         : (WZERO * WROW);
                    const half8 a  = *(const half8*)(wls + woff);
                    const half8 xb = *(const half8*)(xls + (2 * rp + g) * XROW + b * 4);
                    const f32x16 u = __builtin_amdgcn_mfma_f32_32x32x16_f16(a, xb, zero16, 0, 0, 0);
                    // partial dots over this lane's 8 o's; r'=0 rows in u[0..7], r'=1 in u[8..15]
                    const float p0 = u[0] * va.x + u[1] * va.y + u[2] * va.z + u[3] * va.w
                                   + u[4] * vb.x + u[5] * vb.y + u[6] * vb.z + u[7] * vb.w;
                    const float p1 = u[8] * va.x + u[9] * va.y + u[10] * va.z + u[11] * va.w
                                   + u[12] * vb.x + u[13] * vb.y + u[14] * vb.z + u[15] * vb.w;
                    // exchange the partial we DON'T keep; keep p_g (r = 2rp+g)
                    const float send = g ? p0 : p1;
                    const float recv = __shfl_xor(send, 32);
                    const float pg = (g ? p1 : p0) + recv;
                    const float ee = __expf(pg);
                    e[c][rp] = ee;
                    dacc[rp] += ee;
                }
            }
#pragma unroll
            for (int rp = 0; rp < 4; ++rp) dinv[rp] = 1.0f / dacc[rp];
        }

        // ---- phase 3: weighted accumulation (no dot/exp recompute) ----
#pragma unroll
        for (int c = 0; c < C_; ++c) {
            f32x16 acc;
#pragma unroll
            for (int rp = 0; rp < 4; ++rp) {
                const int woff = act ? ((c * 8 + 2 * rp + g) * WROW + o_m * 4)
                                     : (WZERO * WROW);
                const half8 a  = *(const half8*)(wls + woff);
                const half8 xb = *(const half8*)(xls + (2 * rp + g) * XROW + b * 4);
                const f32x16 u = __builtin_amdgcn_mfma_f32_32x32x16_f16(a, xb, zero16, 0, 0, 0);
                const float w_own = e[c][rp] * dinv[rp];       // weight for r = 2rp+g
                const float w_oth = __shfl_xor(w_own, 32);     // partner's (r = 2rp+(1-g))
                const float c0 = g ? w_oth : w_own;            // r' = 0 rows (u[0..7])
                const float c1 = g ? w_own : w_oth;            // r' = 1 rows (u[8..15])
                if (rp == 0) {
#pragma unroll
                    for (int j = 0; j < 8; ++j)  acc[j] = c0 * u[j];
#pragma unroll
                    for (int j = 8; j < 16; ++j) acc[j] = c1 * u[j];
                } else {
#pragma unroll
                    for (int j = 0; j < 8; ++j)  acc[j] += c0 * u[j];
#pragma unroll
                    for (int j = 8; j < 16; ++j) acc[j] += c1 * u[j];
                }
            }
            const float f0 = acc[0] + acc[8],  f1 = acc[1] + acc[9];
            const float f2 = acc[2] + acc[10], f3 = acc[3] + acc[11];
            const float f4 = acc[4] + acc[12], f5 = acc[5] + acc[13];
            const float f6 = acc[6] + acc[14], f7 = acc[7] + acc[15];
            __half* pp = part + (((size_t)blockIdx.x * C_ + c) * B_ + b) * O_;
            *(uint2*)(pp + 4 * g)     = make_uint2(pk2(f0, f1), pk2(f2, f3));
            *(uint2*)(pp + 8 + 4 * g) = make_uint2(pk2(f4, f5), pk2(f6, f7));
        }
    } else {
        // ================= mode 0: uniform weights 0.1 =================
#pragma unroll
        for (int c = 0; c < C_; ++c) {
            f32x16 acc = zero16;
#pragma unroll
            for (int rp = 0; rp < 4; ++rp) {
                const int woff = act ? ((c * 8 + 2 * rp + g) * WROW + o_m * 4)
                                     : (WZERO * WROW);
                const half8 a  = *(const half8*)(wls + woff);
                const half8 xb = *(const half8*)(xls + (2 * rp + g) * XROW + b * 4);
                acc = __builtin_amdgcn_mfma_f32_32x32x16_f16(a, xb, acc, 0, 0, 0);
            }
            const float f0 = (acc[0] + acc[8])  * 0.1f, f1 = (acc[1] + acc[9])  * 0.1f;
            const float f2 = (acc[2] + acc[10]) * 0.1f, f3 = (acc[3] + acc[11]) * 0.1f;
            const float f4 = (acc[4] + acc[12]) * 0.1f, f5 = (acc[5] + acc[13]) * 0.1f;
            const float f6 = (acc[6] + acc[14]) * 0.1f, f7 = (acc[7] + acc[15]) * 0.1f;
            __half* pp = part + (((size_t)blockIdx.x * C_ + c) * B_ + b) * O_;
            *(uint2*)(pp + 4 * g)     = make_uint2(pk2(f0, f1), pk2(f2, f3));
            *(uint2*)(pp + 8 + 4 * g) = make_uint2(pk2(f4, f5), pk2(f6, f7));
        }
    }
}

// ---------------------------------------------------------------------------
// reduce1: part2[by][..] = sum of 64 slot-partials. Vectorized: each thread
// owns 8 consecutive halfs, loads uint4 (16B/lane, fully coalesced: a wave
// covers 1KB contiguous per slot). grid (10,16), block 256.
// ---------------------------------------------------------------------------
__global__ __launch_bounds__(256) void reduce1(const __half* __restrict__ part,
                                               float* __restrict__ part2) {
    const int t8 = blockIdx.x * 256 + threadIdx.x;      // 0..2559
    const __half* p = part + (size_t)(blockIdx.y * 64) * SBO + (size_t)t8 * 8;
    float s0 = 0.f, s1 = 0.f, s2 = 0.f, s3 = 0.f;
    float s4 = 0.f, s5 = 0.f, s6 = 0.f, s7 = 0.f;
#pragma unroll 8
    for (int s = 0; s < 64; ++s) {
        const uint4 v = *(const uint4*)(p + (size_t)s * SBO);
        const __half2 h0 = *(const __half2*)&v.x;
        const __half2 h1 = *(const __half2*)&v.y;
        const __half2 h2 = *(const __half2*)&v.z;
        const __half2 h3 = *(const __half2*)&v.w;
        const float2 f0 = __half22float2(h0);
        const float2 f1 = __half22float2(h1);
        const float2 f2 = __half22float2(h2);
        const float2 f3 = __half22float2(h3);
        s0 += f0.x; s1 += f0.y; s2 += f1.x; s3 += f1.y;
        s4 += f2.x; s5 += f2.y; s6 += f3.x; s7 += f3.y;
    }
    float* q = part2 + (size_t)blockIdx.y * SBO + (size_t)t8 * 8;
    *(float4*)q       = make_float4(s0, s1, s2, s3);
    *(float4*)(q + 4) = make_float4(s4, s5, s6, s7);
}

// ---------------------------------------------------------------------------
// finish_pass: sum 16 fp32 partials + squash. grid 80.
// t = (c*128+b)*16+o; o spans 16 consecutive lanes -> shfl reduce for ||s||^2.
// mode 0: vsum = v; 1: vsum += v; 2: out = v.
// ---------------------------------------------------------------------------
__global__ __launch_bounds__(256) void finish_pass(const float* __restrict__ part2,
                                                   float* __restrict__ vsum,   // [C][B][16]
                                                   float* __restrict__ out,    // [B][C][16]
                                                   int mode) {
    const int t = blockIdx.x * 256 + threadIdx.x;
    float sum = 0.f;
#pragma unroll
    for (int s = 0; s < 16; ++s)
        sum += part2[(size_t)s * SBO + t];

    float sq = sum * sum;
    sq += __shfl_xor(sq, 1);
    sq += __shfl_xor(sq, 2);
    sq += __shfl_xor(sq, 4);
    sq += __shfl_xor(sq, 8);
    const float scale = sq / ((1.0f + sq) * sqrtf(sq + 1e-8f));
    const float v = scale * sum;

    if (mode == 0) {
        vsum[t] = v;
    } else if (mode == 1) {
        vsum[t] += v;
    } else {
        const int o = t & 15, b = (t >> 4) & 127, c = t >> 11;
        out[((size_t)b * C_ + c) * O_ + o] = v;
    }
}

extern "C" void kernel_launch(void* const* d_in, const int* in_sizes, int n_in,
                              void* d_out, int out_size, void* d_ws, size_t ws_size,
                              hipStream_t stream) {
    const float* x = (const float*)d_in[0];   // [B,R,8]
    const float* w = (const float*)d_in[1];   // [C,R,8,16]
    float* out = (float*)d_out;               // [B,C,16]

    __half* part = (__half*)d_ws;                         // 1024*20480 fp16 = 41.9 MB
    float* part2 = (float*)(part + (size_t)1024 * SBO);   // 16*20480 fp32 = 1.3 MB
    float* vsum  = part2 + (size_t)16 * SBO;              // 20480 f ([C][B][16])

    const dim3 fgrid(R_ / 8);        // 1024
    const dim3 rgrid(10, 16);        // 160 blocks, vectorized reduce
    const dim3 ggrid(80);

    // iteration 0 (uniform cij; vsum not read)
    fused_iter<<<fgrid, 256, 0, stream>>>(x, w, vsum, part, 0);
    reduce1<<<rgrid, 256, 0, stream>>>(part, part2);
    finish_pass<<<ggrid, 256, 0, stream>>>(part2, vsum, out, 0);

    // iteration 1
    fused_iter<<<fgrid, 256, 0, stream>>>(x, w, vsum, part, 1);
    reduce1<<<rgrid, 256, 0, stream>>>(part, part2);
    finish_pass<<<ggrid, 256, 0, stream>>>(part2, vsum, out, 1);

    // iteration 2 (final: write out)
    fused_iter<<<fgrid, 256, 0, stream>>>(x, w, vsum, part, 1);
    reduce1<<<rgrid, 256, 0, stream>>>(part, part2);
    finish_pass<<<ggrid, 256, 0, stream>>>(part2, vsum, out, 2);
}

// Round 3
// 218.606 us; speedup vs baseline: 6.6644x; 1.4545x over previous
//
#include <hip/hip_runtime.h>
#include <hip/hip_fp16.h>
#include <math.h>

#define B_ 128
#define C_ 10
#define R_ 8192
#define I_ 8
#define O_ 16

typedef __attribute__((ext_vector_type(8))) _Float16 half8;
typedef __attribute__((ext_vector_type(16))) float f32x16;

#define XROW 512           // uints per x r-row: 128 b * 4
#define WROW 64            // uints per W row: 16 o * 4
#define WZERO 80           // zero-row index (block-diagonal A trick)
#define SBO (C_ * B_ * O_) // 20480

__device__ __forceinline__ unsigned pk2(float a, float b) {
    __half2 h = __floats2half2_rn(a, b);
    return *(unsigned*)&h;
}

// ---------------------------------------------------------------------------
// fused_iter: one routing iteration. grid 1024 (r-tiles of 8), block 256.
// All 10 c's W tiles staged once as fp16 (20.3 KB) + x tile fp16 (16 KB).
// Per (c, r-pair): ONE 32x32x16 f16 MFMA computes u[2r x 16o][32b].
// vs round 0 (all numerically bit-identical; c-loops stay ROLLED — round 2
// showed carried per-c state spills to scratch):
//  - xb fragments hoisted to registers: x-fragment is c-invariant -> read LDS
//    4x instead of 160x per wave (halves LDS-pipe occupancy, kills the 8-way
//    bank-conflict read).
//  - ONE shfl + ONE exp per (c,rp) per phase: each lane keeps only its own
//    r's dot (partner partial via shfl); phase3 gets partner's WEIGHT via a
//    second shfl (identical value to recomputing exp locally).
//  - hoisted zero16 as MFMA C operand; mode 0 chains MFMAs through C.
// Output: part[slot=blockIdx.x][c][b][o] fp16 partial s sums.
// ---------------------------------------------------------------------------
__global__ __launch_bounds__(256, 4) void fused_iter(const float* __restrict__ x,
                                                     const float* __restrict__ w,
                                                     const float* __restrict__ vsum,  // [C][B][16]
                                                     __half* __restrict__ part,
                                                     int mode) {
    __shared__ unsigned xls[8 * XROW];          // 16 KB
    __shared__ unsigned wls[(80 + 1) * WROW];   // 20.25 KB

    const int tid = threadIdx.x;
    const int wave = tid >> 6;
    const int lane = tid & 63;
    const int n = lane & 31;
    const int g = lane >> 5;            // k-half / o-half selector
    const int rp_m = (lane & 31) >> 4;  // r' of this lane's A row
    const int o_m = lane & 15;          // o of this lane's A row
    const int b = wave * 32 + n;        // global batch 0..127
    const int r0 = blockIdx.x * 8;

    // ---- stage x tile fp16: xls[r][b][4 b32], once ----
#pragma unroll
    for (int k = 0; k < 8; ++k) {
        const int f = k * 256 + tid;            // 0..2047
        const int bb = f >> 4;
        const int rr = (f >> 1) & 7;
        const int q = f & 1;
        const float4 v = *(const float4*)(x + ((size_t)bb * R_ + r0 + rr) * 8 + q * 4);
        *(uint2*)(xls + rr * XROW + bb * 4 + q * 2) = make_uint2(pk2(v.x, v.y), pk2(v.z, v.w));
    }
    // ---- stage W for ALL c fp16: wls[c*8+r][o][4 b32], once ----
#pragma unroll
    for (int k = 0; k < 5; ++k) {
        const int id = k * 256 + tid;           // 0..1279 = (c, r, o)
        const int o = id & 15;
        const int r = (id >> 4) & 7;
        const int c = id >> 7;
        const float* wp = w + ((size_t)(c * R_ + r0 + r) * 8) * 16 + o;
        const float f0 = wp[0],  f1 = wp[16],  f2 = wp[32],  f3 = wp[48];
        const float f4 = wp[64], f5 = wp[80],  f6 = wp[96],  f7 = wp[112];
        *(uint4*)(wls + (c * 8 + r) * WROW + o * 4) =
            make_uint4(pk2(f0, f1), pk2(f2, f3), pk2(f4, f5), pk2(f6, f7));
    }
    if (tid < WROW) wls[WZERO * WROW + tid] = 0u;
    __syncthreads();

    const int act = (g == rp_m);

    // hoisted x fragments: c-invariant, 16 VGPRs total, kills 156 LDS reads/wave
    half8 xbr[4];
#pragma unroll
    for (int rp = 0; rp < 4; ++rp)
        xbr[rp] = *(const half8*)(xls + (2 * rp + g) * XROW + b * 4);

    // hoisted zero accumulator: MFMA C operand (D != C), no per-use init
    f32x16 zero16;
#pragma unroll
    for (int j = 0; j < 16; ++j) zero16[j] = 0.f;

    if (mode) {
        // ================= mode 1: softmax-weighted =================
        // ---- phase 2: denominators d[r] = sum_c exp(p[c,r]) ----
        float dinv[4];
        {
            float dacc[4] = {0.f, 0.f, 0.f, 0.f};
#pragma unroll 1
            for (int c = 0; c < C_; ++c) {
                const float4* vp = (const float4*)(vsum + ((size_t)c * B_ + b) * O_ + 4 * g);
                const float4 va = vp[0];   // o = 4g..4g+3
                const float4 vb = vp[2];   // o = 8+4g..
#pragma unroll
                for (int rp = 0; rp < 4; ++rp) {
                    const int woff = act ? ((c * 8 + 2 * rp + g) * WROW + o_m * 4)
                                         : (WZERO * WROW);
                    const half8 a = *(const half8*)(wls + woff);
                    const f32x16 u = __builtin_amdgcn_mfma_f32_32x32x16_f16(a, xbr[rp], zero16, 0, 0, 0);
                    // partial dots over this lane's 8 o's (r'=0 -> u[0..7], r'=1 -> u[8..15])
                    const float p0 = u[0] * va.x + u[1] * va.y + u[2] * va.z + u[3] * va.w
                                   + u[4] * vb.x + u[5] * vb.y + u[6] * vb.z + u[7] * vb.w;
                    const float p1 = u[8] * va.x + u[9] * va.y + u[10] * va.z + u[11] * va.w
                                   + u[12] * vb.x + u[13] * vb.y + u[14] * vb.z + u[15] * vb.w;
                    // exchange the partial we DON'T keep; own r = 2rp+g
                    const float send = g ? p0 : p1;
                    const float recv = __shfl_xor(send, 32);
                    const float pg = (g ? p1 : p0) + recv;
                    dacc[rp] += __expf(pg);
                }
            }
#pragma unroll
            for (int rp = 0; rp < 4; ++rp) dinv[rp] = 1.0f / dacc[rp];
        }

        // ---- phase 3: weighted accumulation ----
#pragma unroll 1
        for (int c = 0; c < C_; ++c) {
            const float4* vp = (const float4*)(vsum + ((size_t)c * B_ + b) * O_ + 4 * g);
            const float4 va = vp[0];
            const float4 vb = vp[2];
            f32x16 acc;
#pragma unroll
            for (int rp = 0; rp < 4; ++rp) {
                const int woff = act ? ((c * 8 + 2 * rp + g) * WROW + o_m * 4)
                                     : (WZERO * WROW);
                const half8 a = *(const half8*)(wls + woff);
                const f32x16 u = __builtin_amdgcn_mfma_f32_32x32x16_f16(a, xbr[rp], zero16, 0, 0, 0);
                const float p0 = u[0] * va.x + u[1] * va.y + u[2] * va.z + u[3] * va.w
                               + u[4] * vb.x + u[5] * vb.y + u[6] * vb.z + u[7] * vb.w;
                const float p1 = u[8] * va.x + u[9] * va.y + u[10] * va.z + u[11] * va.w
                               + u[12] * vb.x + u[13] * vb.y + u[14] * vb.z + u[15] * vb.w;
                const float send = g ? p0 : p1;
                const float recv = __shfl_xor(send, 32);
                const float pg = (g ? p1 : p0) + recv;
                const float w_own = __expf(pg) * dinv[rp];     // weight for r = 2rp+g
                const float w_oth = __shfl_xor(w_own, 32);     // partner's (r = 2rp+(1-g))
                const float c0 = g ? w_oth : w_own;            // r' = 0 rows (u[0..7])
                const float c1 = g ? w_own : w_oth;            // r' = 1 rows (u[8..15])
                if (rp == 0) {
#pragma unroll
                    for (int j = 0; j < 8; ++j)  acc[j] = c0 * u[j];
#pragma unroll
                    for (int j = 8; j < 16; ++j) acc[j] = c1 * u[j];
                } else {
#pragma unroll
                    for (int j = 0; j < 8; ++j)  acc[j] += c0 * u[j];
#pragma unroll
                    for (int j = 8; j < 16; ++j) acc[j] += c1 * u[j];
                }
            }
            const float f0 = acc[0] + acc[8],  f1 = acc[1] + acc[9];
            const float f2 = acc[2] + acc[10], f3 = acc[3] + acc[11];
            const float f4 = acc[4] + acc[12], f5 = acc[5] + acc[13];
            const float f6 = acc[6] + acc[14], f7 = acc[7] + acc[15];
            __half* pp = part + (((size_t)blockIdx.x * C_ + c) * B_ + b) * O_;
            *(uint2*)(pp + 4 * g)     = make_uint2(pk2(f0, f1), pk2(f2, f3));
            *(uint2*)(pp + 8 + 4 * g) = make_uint2(pk2(f4, f5), pk2(f6, f7));
        }
    } else {
        // ================= mode 0: uniform weights 0.1 =================
#pragma unroll 1
        for (int c = 0; c < C_; ++c) {
            f32x16 acc = zero16;
#pragma unroll
            for (int rp = 0; rp < 4; ++rp) {
                const int woff = act ? ((c * 8 + 2 * rp + g) * WROW + o_m * 4)
                                     : (WZERO * WROW);
                const half8 a = *(const half8*)(wls + woff);
                acc = __builtin_amdgcn_mfma_f32_32x32x16_f16(a, xbr[rp], acc, 0, 0, 0);
            }
            const float f0 = (acc[0] + acc[8])  * 0.1f, f1 = (acc[1] + acc[9])  * 0.1f;
            const float f2 = (acc[2] + acc[10]) * 0.1f, f3 = (acc[3] + acc[11]) * 0.1f;
            const float f4 = (acc[4] + acc[12]) * 0.1f, f5 = (acc[5] + acc[13]) * 0.1f;
            const float f6 = (acc[6] + acc[14]) * 0.1f, f7 = (acc[7] + acc[15]) * 0.1f;
            __half* pp = part + (((size_t)blockIdx.x * C_ + c) * B_ + b) * O_;
            *(uint2*)(pp + 4 * g)     = make_uint2(pk2(f0, f1), pk2(f2, f3));
            *(uint2*)(pp + 8 + 4 * g) = make_uint2(pk2(f4, f5), pk2(f6, f7));
        }
    }
}

// ---------------------------------------------------------------------------
// reduce1: part2[by][..] = sum of 64 slot-partials. Vectorized: each thread
// owns 8 consecutive halfs, loads uint4 (16B/lane, fully coalesced).
// grid (10,16), block 256.
// ---------------------------------------------------------------------------
__global__ __launch_bounds__(256) void reduce1(const __half* __restrict__ part,
                                               float* __restrict__ part2) {
    const int t8 = blockIdx.x * 256 + threadIdx.x;      // 0..2559
    const __half* p = part + (size_t)(blockIdx.y * 64) * SBO + (size_t)t8 * 8;
    float s0 = 0.f, s1 = 0.f, s2 = 0.f, s3 = 0.f;
    float s4 = 0.f, s5 = 0.f, s6 = 0.f, s7 = 0.f;
#pragma unroll 8
    for (int s = 0; s < 64; ++s) {
        const uint4 v = *(const uint4*)(p + (size_t)s * SBO);
        const __half2 h0 = *(const __half2*)&v.x;
        const __half2 h1 = *(const __half2*)&v.y;
        const __half2 h2 = *(const __half2*)&v.z;
        const __half2 h3 = *(const __half2*)&v.w;
        const float2 f0 = __half22float2(h0);
        const float2 f1 = __half22float2(h1);
        const float2 f2 = __half22float2(h2);
        const float2 f3 = __half22float2(h3);
        s0 += f0.x; s1 += f0.y; s2 += f1.x; s3 += f1.y;
        s4 += f2.x; s5 += f2.y; s6 += f3.x; s7 += f3.y;
    }
    float* q = part2 + (size_t)blockIdx.y * SBO + (size_t)t8 * 8;
    *(float4*)q       = make_float4(s0, s1, s2, s3);
    *(float4*)(q + 4) = make_float4(s4, s5, s6, s7);
}

// ---------------------------------------------------------------------------
// finish_pass: sum 16 fp32 partials + squash. grid 80.
// t = (c*128+b)*16+o; o spans 16 consecutive lanes -> shfl reduce for ||s||^2.
// mode 0: vsum = v; 1: vsum += v; 2: out = v.
// ---------------------------------------------------------------------------
__global__ __launch_bounds__(256) void finish_pass(const float* __restrict__ part2,
                                                   float* __restrict__ vsum,   // [C][B][16]
                                                   float* __restrict__ out,    // [B][C][16]
                                                   int mode) {
    const int t = blockIdx.x * 256 + threadIdx.x;
    float sum = 0.f;
#pragma unroll
    for (int s = 0; s < 16; ++s)
        sum += part2[(size_t)s * SBO + t];

    float sq = sum * sum;
    sq += __shfl_xor(sq, 1);
    sq += __shfl_xor(sq, 2);
    sq += __shfl_xor(sq, 4);
    sq += __shfl_xor(sq, 8);
    const float scale = sq / ((1.0f + sq) * sqrtf(sq + 1e-8f));
    const float v = scale * sum;

    if (mode == 0) {
        vsum[t] = v;
    } else if (mode == 1) {
        vsum[t] += v;
    } else {
        const int o = t & 15, b = (t >> 4) & 127, c = t >> 11;
        out[((size_t)b * C_ + c) * O_ + o] = v;
    }
}

extern "C" void kernel_launch(void* const* d_in, const int* in_sizes, int n_in,
                              void* d_out, int out_size, void* d_ws, size_t ws_size,
                              hipStream_t stream) {
    const float* x = (const float*)d_in[0];   // [B,R,8]
    const float* w = (const float*)d_in[1];   // [C,R,8,16]
    float* out = (float*)d_out;               // [B,C,16]

    __half* part = (__half*)d_ws;                         // 1024*20480 fp16 = 41.9 MB
    float* part2 = (float*)(part + (size_t)1024 * SBO);   // 16*20480 fp32 = 1.3 MB
    float* vsum  = part2 + (size_t)16 * SBO;              // 20480 f ([C][B][16])

    const dim3 fgrid(R_ / 8);        // 1024
    const dim3 rgrid(10, 16);        // 160 blocks, vectorized reduce
    const dim3 ggrid(80);

    // iteration 0 (uniform cij; vsum not read)
    fused_iter<<<fgrid, 256, 0, stream>>>(x, w, vsum, part, 0);
    reduce1<<<rgrid, 256, 0, stream>>>(part, part2);
    finish_pass<<<ggrid, 256, 0, stream>>>(part2, vsum, out, 0);

    // iteration 1
    fused_iter<<<fgrid, 256, 0, stream>>>(x, w, vsum, part, 1);
    reduce1<<<rgrid, 256, 0, stream>>>(part, part2);
    finish_pass<<<ggrid, 256, 0, stream>>>(part2, vsum, out, 1);

    // iteration 2 (final: write out)
    fused_iter<<<fgrid, 256, 0, stream>>>(x, w, vsum, part, 1);
    reduce1<<<rgrid, 256, 0, stream>>>(part, part2);
    finish_pass<<<ggrid, 256, 0, stream>>>(part2, vsum, out, 2);
}